// Round 1
// baseline (21010.435 us; speedup 1.0000x reference)
//
#include <hip/hip_runtime.h>
#include <hip/hip_bf16.h>
#include <cstddef>

// Problem constants
#define B_   1024
#define C_   3
#define NP_  10
#define PL_  100
#define D_   768
#define H_   12
#define L_   12
#define N_   12   // NP + 2
#define HD_  64

// ---------------------------------------------------------------------------
// Block-wide reduction of two floats across 256 threads (4 waves of 64).
// Result broadcast to all threads.
// ---------------------------------------------------------------------------
__device__ __forceinline__ void block_reduce2(float& a, float& b) {
    __shared__ float sa[4], sb[4];
#pragma unroll
    for (int off = 32; off > 0; off >>= 1) {
        a += __shfl_down(a, off);
        b += __shfl_down(b, off);
    }
    int wid = threadIdx.x >> 6, lane = threadIdx.x & 63;
    __syncthreads();
    if (lane == 0) { sa[wid] = a; sb[wid] = b; }
    __syncthreads();
    if (threadIdx.x == 0) {
        float ta = 0.f, tb = 0.f;
#pragma unroll
        for (int i = 0; i < 4; ++i) { ta += sa[i]; tb += sb[i]; }
        sa[0] = ta; sb[0] = tb;
    }
    __syncthreads();
    a = sa[0]; b = sb[0];
}

// ---------------------------------------------------------------------------
// Generic tiled fp32 GEMM:  C[M,N] = op(A)[M,K] @ W[K,N] + bias (+res) (relu?)
// amode 0: A row-major [M,K]
// amode 1: token-select: logical row r -> physical row (r/10)*12 + r%10 of A
//          (extract the NP patch tokens out of the N=12 token rows)
// amode 2: patch gather: A(r,k) = patches[((b*3+c)*10+n)*100+p],
//          b=r/10, n=r%10, c=k/100, p=k%100  (the flat_raw transpose)
// All K and N used are multiples of 4, so float4 chunks are all-in/all-out.
// ---------------------------------------------------------------------------
#define BM 64
#define BN 64
#define BK 16

__global__ __launch_bounds__(256) void gemm_kernel(
    const float* __restrict__ A, const float* __restrict__ W,
    const float* __restrict__ bias, const float* __restrict__ res,
    float* __restrict__ C, int M, int N, int K, int amode, int relu)
{
    __shared__ float As[BK][BM];
    __shared__ float Ws[BK][BN];

    const int tid = threadIdx.x;
    const int tx = tid & 15, ty = tid >> 4;
    const int m0 = blockIdx.y * BM, n0 = blockIdx.x * BN;

    float acc[4][4] = {};

    const int am  = tid & 63;        // A-tile row
    const int akq = tid >> 6;        // A-tile k quad (0..3)
    const int wn  = (tid & 15) * 4;  // W-tile col
    const int wk  = tid >> 4;        // W-tile k (0..15)

    for (int k0 = 0; k0 < K; k0 += BK) {
        // ---- stage A tile (stored transposed: As[k][m]) ----
        float4 av = make_float4(0.f, 0.f, 0.f, 0.f);
        int gm = m0 + am;
        int gk = k0 + akq * 4;
        if (gm < M && gk < K) {
            if (amode == 0) {
                av = *(const float4*)(A + (size_t)gm * K + gk);
            } else if (amode == 1) {
                int r = (gm / 10) * 12 + (gm % 10);
                av = *(const float4*)(A + (size_t)r * K + gk);
            } else {
                int bb = gm / 10, n = gm % 10, c = gk / 100, p = gk % 100;
                av = *(const float4*)(A + (size_t)(((bb * 3 + c) * 10 + n) * 100 + p));
            }
        }
        As[akq * 4 + 0][am] = av.x;
        As[akq * 4 + 1][am] = av.y;
        As[akq * 4 + 2][am] = av.z;
        As[akq * 4 + 3][am] = av.w;

        // ---- stage W tile ----
        float4 wv = make_float4(0.f, 0.f, 0.f, 0.f);
        int gkw = k0 + wk, gn = n0 + wn;
        if (gkw < K && gn < N)
            wv = *(const float4*)(W + (size_t)gkw * N + gn);
        *(float4*)&Ws[wk][wn] = wv;

        __syncthreads();

#pragma unroll
        for (int kk = 0; kk < BK; ++kk) {
            float4 a = *(const float4*)&As[kk][ty * 4];
            float4 b = *(const float4*)&Ws[kk][tx * 4];
            acc[0][0] += a.x * b.x; acc[0][1] += a.x * b.y; acc[0][2] += a.x * b.z; acc[0][3] += a.x * b.w;
            acc[1][0] += a.y * b.x; acc[1][1] += a.y * b.y; acc[1][2] += a.y * b.z; acc[1][3] += a.y * b.w;
            acc[2][0] += a.z * b.x; acc[2][1] += a.z * b.y; acc[2][2] += a.z * b.z; acc[2][3] += a.z * b.w;
            acc[3][0] += a.w * b.x; acc[3][1] += a.w * b.y; acc[3][2] += a.w * b.z; acc[3][3] += a.w * b.w;
        }
        __syncthreads();
    }

#pragma unroll
    for (int i = 0; i < 4; ++i) {
        int row = m0 + ty * 4 + i;
        if (row >= M) continue;
#pragma unroll
        for (int j = 0; j < 4; ++j) {
            int col = n0 + tx * 4 + j;
            if (col >= N) continue;
            float v = acc[i][j] + bias[col];
            if (relu) v = fmaxf(v, 0.f);
            if (res) v += res[(size_t)row * N + col];
            C[(size_t)row * N + col] = v;
        }
    }
}

// ---------------------------------------------------------------------------
// LayerNorm over last dim (768). One block per token row.
// ---------------------------------------------------------------------------
__global__ __launch_bounds__(256) void ln_kernel(
    const float* __restrict__ X, const float* __restrict__ g,
    const float* __restrict__ b, float* __restrict__ O)
{
    const int row = blockIdx.x;
    const int t = threadIdx.x;
    const float* x = X + (size_t)row * D_;
    float v0 = x[t], v1 = x[t + 256], v2 = x[t + 512];
    float s  = v0 + v1 + v2;
    float ss = v0 * v0 + v1 * v1 + v2 * v2;
    block_reduce2(s, ss);
    float mean = s * (1.f / D_);
    float var  = ss * (1.f / D_) - mean * mean;
    float rstd = rsqrtf(var + 1e-5f);
    float* o = O + (size_t)row * D_;
    o[t]       = (v0 - mean) * rstd * g[t]       + b[t];
    o[t + 256] = (v1 - mean) * rstd * g[t + 256] + b[t + 256];
    o[t + 512] = (v2 - mean) * rstd * g[t + 512] + b[t + 512];
}

// ---------------------------------------------------------------------------
// Assemble token sequence (patch tokens w/ mask, stats token, topo token)
// and apply embedding LayerNorm. One block per (b, n).
// ---------------------------------------------------------------------------
__global__ __launch_bounds__(256) void assemble_ln_kernel(
    const float* __restrict__ pvec, const float* __restrict__ svec,
    const float* __restrict__ gvec, const int* __restrict__ mask,
    const float* __restrict__ mtok, const float* __restrict__ g,
    const float* __restrict__ b, float* __restrict__ O)
{
    const int row = blockIdx.x;            // b*12 + n
    const int bb = row / N_, n = row % N_;
    const int t = threadIdx.x;
    float v0, v1, v2;
    if (n < NP_) {
        if (mask[bb * NP_ + n]) {
            v0 = mtok[t]; v1 = mtok[t + 256]; v2 = mtok[t + 512];
        } else {
            const float* p = pvec + (size_t)(bb * NP_ + n) * D_;
            v0 = p[t]; v1 = p[t + 256]; v2 = p[t + 512];
        }
    } else if (n == NP_) {
        const float* p = svec + (size_t)bb * D_;
        v0 = p[t]; v1 = p[t + 256]; v2 = p[t + 512];
    } else {
        const float* p = gvec + (size_t)bb * D_;
        v0 = p[t]; v1 = p[t + 256]; v2 = p[t + 512];
    }
    float s  = v0 + v1 + v2;
    float ss = v0 * v0 + v1 * v1 + v2 * v2;
    block_reduce2(s, ss);
    float mean = s * (1.f / D_);
    float var  = ss * (1.f / D_) - mean * mean;
    float rstd = rsqrtf(var + 1e-5f);
    float* o = O + (size_t)row * D_;
    o[t]       = (v0 - mean) * rstd * g[t]       + b[t];
    o[t + 256] = (v1 - mean) * rstd * g[t + 256] + b[t + 256];
    o[t + 512] = (v2 - mean) * rstd * g[t + 512] + b[t + 512];
}

// ---------------------------------------------------------------------------
// Fused attention: one wave (64 threads) per (b, head).
// Loads q/k/v (12x64 each) to LDS, applies RoPE, 12x12 scores + softmax,
// attn @ v, writes out in (B, N, D) layout.
// ---------------------------------------------------------------------------
__global__ __launch_bounds__(64) void attn_kernel(
    const float* __restrict__ QKV, float* __restrict__ OUT)
{
    const int bh = blockIdx.x;
    const int bb = bh / H_, h = bh % H_;
    const int t = threadIdx.x;

    __shared__ float q[N_][HD_], k[N_][HD_], v[N_][HD_], p[N_][N_];

    const float* base = QKV + (size_t)bb * N_ * (3 * D_) + h * HD_;
#pragma unroll
    for (int n = 0; n < N_; ++n) {
        q[n][t] = base[n * (3 * D_) + t];
        k[n][t] = base[n * (3 * D_) + D_ + t];
        v[n][t] = base[n * (3 * D_) + 2 * D_ + t];
    }
    __syncthreads();

    // RoPE on q, k: pair i handled by thread i (i<32)
    if (t < 32) {
        // freq_i = 10000^(-i/32) = 2^(-i * log2(10000)/32)
        float freq = exp2f(-(float)t * (13.287712379549449f / 32.0f));
#pragma unroll
        for (int n = 0; n < N_; ++n) {
            float ang = (float)n * freq;
            float sn, cs;
            sincosf(ang, &sn, &cs);
            float xr = q[n][2 * t], xi = q[n][2 * t + 1];
            q[n][2 * t]     = xr * cs - xi * sn;
            q[n][2 * t + 1] = xr * sn + xi * cs;
            xr = k[n][2 * t]; xi = k[n][2 * t + 1];
            k[n][2 * t]     = xr * cs - xi * sn;
            k[n][2 * t + 1] = xr * sn + xi * cs;
        }
    }
    __syncthreads();

    // scores
    for (int idx = t; idx < N_ * N_; idx += 64) {
        int i = idx / N_, j = idx % N_;
        float s = 0.f;
#pragma unroll
        for (int d = 0; d < HD_; ++d) s += q[i][d] * k[j][d];
        p[i][j] = s * 0.125f;   // 1/sqrt(64)
    }
    __syncthreads();

    // softmax per row
    if (t < N_) {
        float mx = -1e30f;
#pragma unroll
        for (int j = 0; j < N_; ++j) mx = fmaxf(mx, p[t][j]);
        float e[N_], sum = 0.f;
#pragma unroll
        for (int j = 0; j < N_; ++j) { e[j] = expf(p[t][j] - mx); sum += e[j]; }
        float inv = 1.f / sum;
#pragma unroll
        for (int j = 0; j < N_; ++j) p[t][j] = e[j] * inv;
    }
    __syncthreads();

    // out[i][t] = sum_j p[i][j] * v[j][t]
#pragma unroll
    for (int i = 0; i < N_; ++i) {
        float o = 0.f;
#pragma unroll
        for (int j = 0; j < N_; ++j) o += p[i][j] * v[j][t];
        OUT[((size_t)bb * N_ + i) * D_ + h * HD_ + t] = o;
    }
}

// ---------------------------------------------------------------------------
// Loss: per-(b,n) partial sums of masked squared error.
// target(b,n,k) = patches[((b*3 + k/100)*10 + n)*100 + k%100]
// ---------------------------------------------------------------------------
__global__ __launch_bounds__(256) void loss_partial_kernel(
    const float* __restrict__ pred, const float* __restrict__ patches,
    const int* __restrict__ mask, float* __restrict__ part)
{
    const int row = blockIdx.x;           // b*10 + n
    const int t = threadIdx.x;
    if (!mask[row]) {
        if (t == 0) part[row] = 0.f;
        return;
    }
    const int bb = row / NP_, n = row % NP_;
    float s = 0.f;
    for (int kk = t; kk < C_ * PL_; kk += 256) {
        int c = kk / PL_, pp = kk % PL_;
        float tgt = patches[((size_t)(bb * C_ + c) * NP_ + n) * PL_ + pp];
        float d = pred[(size_t)row * (C_ * PL_) + kk] - tgt;
        s += d * d;
    }
    float dummy = 0.f;
    block_reduce2(s, dummy);
    if (t == 0) part[row] = s;
}

__global__ __launch_bounds__(256) void loss_final_kernel(
    const float* __restrict__ part, const int* __restrict__ mask,
    float* __restrict__ out)
{
    const int t = threadIdx.x;
    float s = 0.f, cnt = 0.f;
    for (int i = t; i < B_ * NP_; i += 256) {
        s += part[i];
        cnt += (float)mask[i];
    }
    block_reduce2(s, cnt);
    if (t == 0) out[0] = s / (cnt * (float)(C_ * PL_));
}

// ---------------------------------------------------------------------------
// Host launch
// ---------------------------------------------------------------------------
extern "C" void kernel_launch(void* const* d_in, const int* in_sizes, int n_in,
                              void* d_out, int out_size, void* d_ws, size_t ws_size,
                              hipStream_t stream) {
    const float* patches = (const float*)d_in[0];
    const float* stats   = (const float*)d_in[1];
    const float* topo    = (const float*)d_in[2];
    const int*   mask    = (const int*)d_in[3];
    const float* patch_w = (const float*)d_in[4];
    const float* patch_b = (const float*)d_in[5];
    const float* stat_w  = (const float*)d_in[6];
    const float* stat_b  = (const float*)d_in[7];
    const float* topo_w  = (const float*)d_in[8];
    const float* topo_b  = (const float*)d_in[9];
    const float* mtok    = (const float*)d_in[10];
    const float* emb_g   = (const float*)d_in[11];
    const float* emb_b   = (const float*)d_in[12];
    const float* ln1_g   = (const float*)d_in[13];
    const float* ln1_b   = (const float*)d_in[14];
    const float* qkv_w   = (const float*)d_in[15];
    const float* qkv_b   = (const float*)d_in[16];
    const float* proj_w  = (const float*)d_in[17];
    const float* proj_b  = (const float*)d_in[18];
    const float* ln2_g   = (const float*)d_in[19];
    const float* ln2_b   = (const float*)d_in[20];
    const float* f1_w    = (const float*)d_in[21];
    const float* f1_b    = (const float*)d_in[22];
    const float* f2_w    = (const float*)d_in[23];
    const float* f2_b    = (const float*)d_in[24];
    const float* h1_w    = (const float*)d_in[25];
    const float* h1_b    = (const float*)d_in[26];
    const float* h2_w    = (const float*)d_in[27];
    const float* h2_b    = (const float*)d_in[28];

    float* ws = (float*)d_ws;
    const size_t XSZ = (size_t)B_ * N_ * D_;          // 9,437,184
    float* X    = ws;
    float* Hb   = X + XSZ;
    float* QKV  = Hb + XSZ;                           // 28,311,552
    float* PVEC = QKV + (size_t)B_ * N_ * 3 * D_;     // 7,864,320
    float* SVEC = PVEC + (size_t)B_ * NP_ * D_;       // 786,432
    float* GVEC = SVEC + (size_t)B_ * D_;             // 786,432
    float* PART = GVEC + (size_t)B_ * D_;             // 10,240
    float* MID  = QKV;   // B*N*2D = 18.9M <= 28.3M
    float* PMID = PVEC;  // B*NP*D
    float* PRED = QKV;   // B*NP*300

    const dim3 blk(256);

    // ---- embed ----
    gemm_kernel<<<dim3(D_ / 64, (B_ * NP_) / 64), blk, 0, stream>>>(
        patches, patch_w, patch_b, nullptr, PVEC, B_ * NP_, D_, C_ * PL_, 2, 0);
    gemm_kernel<<<dim3(D_ / 64, B_ / 64), blk, 0, stream>>>(
        stats, stat_w, stat_b, nullptr, SVEC, B_, D_, 56, 0, 0);
    gemm_kernel<<<dim3(D_ / 64, B_ / 64), blk, 0, stream>>>(
        topo, topo_w, topo_b, nullptr, GVEC, B_, D_, 24, 0, 0);
    assemble_ln_kernel<<<B_ * N_, blk, 0, stream>>>(
        PVEC, SVEC, GVEC, mask, mtok, emb_g, emb_b, X);

    // ---- transformer layers ----
    for (int l = 0; l < L_; ++l) {
        ln_kernel<<<B_ * N_, blk, 0, stream>>>(X, ln1_g + l * D_, ln1_b + l * D_, Hb);
        gemm_kernel<<<dim3((3 * D_) / 64, (B_ * N_) / 64), blk, 0, stream>>>(
            Hb, qkv_w + (size_t)l * D_ * 3 * D_, qkv_b + l * 3 * D_, nullptr, QKV,
            B_ * N_, 3 * D_, D_, 0, 0);
        attn_kernel<<<B_ * H_, dim3(64), 0, stream>>>(QKV, Hb);
        gemm_kernel<<<dim3(D_ / 64, (B_ * N_) / 64), blk, 0, stream>>>(
            Hb, proj_w + (size_t)l * D_ * D_, proj_b + l * D_, X, X,
            B_ * N_, D_, D_, 0, 0);
        ln_kernel<<<B_ * N_, blk, 0, stream>>>(X, ln2_g + l * D_, ln2_b + l * D_, Hb);
        gemm_kernel<<<dim3((2 * D_) / 64, (B_ * N_) / 64), blk, 0, stream>>>(
            Hb, f1_w + (size_t)l * D_ * 2 * D_, f1_b + l * 2 * D_, nullptr, MID,
            B_ * N_, 2 * D_, D_, 0, 1);
        gemm_kernel<<<dim3(D_ / 64, (B_ * N_) / 64), blk, 0, stream>>>(
            MID, f2_w + (size_t)l * 2 * D_ * D_, f2_b + l * D_, X, X,
            B_ * N_, D_, 2 * D_, 0, 0);
    }

    // ---- head + loss ----
    gemm_kernel<<<dim3(D_ / 64, (B_ * NP_) / 64), blk, 0, stream>>>(
        X, h1_w, h1_b, nullptr, PMID, B_ * NP_, D_, D_, 1, 1);
    gemm_kernel<<<dim3((C_ * PL_ + 63) / 64, (B_ * NP_) / 64), blk, 0, stream>>>(
        PMID, h2_w, h2_b, nullptr, PRED, B_ * NP_, C_ * PL_, D_, 0, 0);
    loss_partial_kernel<<<B_ * NP_, blk, 0, stream>>>(PRED, patches, mask, PART);
    loss_final_kernel<<<1, blk, 0, stream>>>(PART, mask, (float*)d_out);
}

// Round 3
// 5265.653 us; speedup vs baseline: 3.9901x; 3.9901x over previous
//
#include <hip/hip_runtime.h>
#include <hip/hip_bf16.h>
#include <cstddef>

// Problem constants
#define B_   1024
#define C_   3
#define NP_  10
#define PL_  100
#define D_   768
#define H_   12
#define L_   12
#define N_   12   // NP + 2
#define HD_  64

typedef __attribute__((ext_vector_type(8))) short short8;   // 8 x bf16 (4 VGPRs)
typedef __attribute__((ext_vector_type(4))) float float4v;  // 4 x f32 acc

__device__ __forceinline__ ushort f2bf(float x) {
    __hip_bfloat16 h = __float2bfloat16(x);
    return *(ushort*)&h;
}
__device__ __forceinline__ float bf2f(ushort u) {
    union { unsigned u32; float f; } x; x.u32 = ((unsigned)u) << 16; return x.f;
}

// ---------------------------------------------------------------------------
// Block-wide reduction of two floats across 256 threads (4 waves of 64).
// ---------------------------------------------------------------------------
__device__ __forceinline__ void block_reduce2(float& a, float& b) {
    __shared__ float sa[4], sb[4];
#pragma unroll
    for (int off = 32; off > 0; off >>= 1) {
        a += __shfl_down(a, off);
        b += __shfl_down(b, off);
    }
    int wid = threadIdx.x >> 6, lane = threadIdx.x & 63;
    __syncthreads();
    if (lane == 0) { sa[wid] = a; sb[wid] = b; }
    __syncthreads();
    if (threadIdx.x == 0) {
        float ta = 0.f, tb = 0.f;
#pragma unroll
        for (int i = 0; i < 4; ++i) { ta += sa[i]; tb += sb[i]; }
        sa[0] = ta; sb[0] = tb;
    }
    __syncthreads();
    a = sa[0]; b = sb[0];
}

// ---------------------------------------------------------------------------
// fp32 tiled GEMM (kept for the tiny embed GEMMs: K=300/56/24).
// amode 0: row-major A. amode 2: patch gather (flat_raw transpose).
// ---------------------------------------------------------------------------
#define BM 64
#define BN 64
#define BK 16

__global__ __launch_bounds__(256) void gemm_kernel(
    const float* __restrict__ A, const float* __restrict__ W,
    const float* __restrict__ bias, const float* __restrict__ res,
    float* __restrict__ C, int M, int N, int K, int amode, int relu)
{
    __shared__ float As[BK][BM];
    __shared__ float Ws[BK][BN];

    const int tid = threadIdx.x;
    const int tx = tid & 15, ty = tid >> 4;
    const int m0 = blockIdx.y * BM, n0 = blockIdx.x * BN;

    float acc[4][4] = {};

    const int am  = tid & 63;
    const int akq = tid >> 6;
    const int wn  = (tid & 15) * 4;
    const int wk  = tid >> 4;

    for (int k0 = 0; k0 < K; k0 += BK) {
        float4 av = make_float4(0.f, 0.f, 0.f, 0.f);
        int gm = m0 + am;
        int gk = k0 + akq * 4;
        if (gm < M && gk < K) {
            if (amode == 0) {
                av = *(const float4*)(A + (size_t)gm * K + gk);
            } else {
                int bb = gm / 10, n = gm % 10, c = gk / 100, p = gk % 100;
                av = *(const float4*)(A + (size_t)(((bb * 3 + c) * 10 + n) * 100 + p));
            }
        }
        As[akq * 4 + 0][am] = av.x;
        As[akq * 4 + 1][am] = av.y;
        As[akq * 4 + 2][am] = av.z;
        As[akq * 4 + 3][am] = av.w;

        float4 wv = make_float4(0.f, 0.f, 0.f, 0.f);
        int gkw = k0 + wk, gn = n0 + wn;
        if (gkw < K && gn < N)
            wv = *(const float4*)(W + (size_t)gkw * N + gn);
        *(float4*)&Ws[wk][wn] = wv;

        __syncthreads();

#pragma unroll
        for (int kk = 0; kk < BK; ++kk) {
            float4 a = *(const float4*)&As[kk][ty * 4];
            float4 b = *(const float4*)&Ws[kk][tx * 4];
            acc[0][0] += a.x * b.x; acc[0][1] += a.x * b.y; acc[0][2] += a.x * b.z; acc[0][3] += a.x * b.w;
            acc[1][0] += a.y * b.x; acc[1][1] += a.y * b.y; acc[1][2] += a.y * b.z; acc[1][3] += a.y * b.w;
            acc[2][0] += a.z * b.x; acc[2][1] += a.z * b.y; acc[2][2] += a.z * b.z; acc[2][3] += a.z * b.w;
            acc[3][0] += a.w * b.x; acc[3][1] += a.w * b.y; acc[3][2] += a.w * b.z; acc[3][3] += a.w * b.w;
        }
        __syncthreads();
    }

#pragma unroll
    for (int i = 0; i < 4; ++i) {
        int row = m0 + ty * 4 + i;
        if (row >= M) continue;
#pragma unroll
        for (int j = 0; j < 4; ++j) {
            int col = n0 + tx * 4 + j;
            if (col >= N) continue;
            float v = acc[i][j] + bias[col];
            if (relu) v = fmaxf(v, 0.f);
            if (res) v += res[(size_t)row * N + col];
            C[(size_t)row * N + col] = v;
        }
    }
}

// ---------------------------------------------------------------------------
// Weight convert+transpose: fp32 [K,N] row-major -> bf16 [N,K] row-major.
// ---------------------------------------------------------------------------
__global__ __launch_bounds__(256) void transpose_bf16(
    const float* __restrict__ in, ushort* __restrict__ out, int K, int N)
{
    __shared__ float t[32][33];
    const int tx = threadIdx.x & 31, ty = threadIdx.x >> 5;  // 32 x 8
    const int k0 = blockIdx.y * 32, n0 = blockIdx.x * 32;
#pragma unroll
    for (int i = 0; i < 4; ++i) {
        int k = k0 + ty + i * 8, n = n0 + tx;
        t[ty + i * 8][tx] = (k < K && n < N) ? in[(size_t)k * N + n] : 0.f;
    }
    __syncthreads();
#pragma unroll
    for (int i = 0; i < 4; ++i) {
        int n = n0 + ty + i * 8, k = k0 + tx;
        if (n < N && k < K)
            out[(size_t)n * K + k] = f2bf(t[tx][ty + i * 8]);
    }
}

// ---------------------------------------------------------------------------
// bf16 MFMA GEMM: out[M,N] = A[M,K](bf16) @ Wt[N,K](bf16)^T + bias (+res)
// 128x128 tile, BK=32, 4 waves x (4x4 of 16x16x32 subtiles).
// M, K multiples of 128/32; N guarded. obf16: store bf16 instead of fp32.
// Staging: 256 threads x 16 shorts (2x short8) = 128 rows x 32 cols. (R2 bug
// fixed: previously only half the tile was staged.)
// ---------------------------------------------------------------------------
#define LDT 40   // padded LDS row (shorts): 80B -> 2-way bank alias (free)

__global__ __launch_bounds__(256) void mfma_gemm(
    const ushort* __restrict__ A, const ushort* __restrict__ Wt,
    const float* __restrict__ bias, const float* __restrict__ res,
    void* __restrict__ outp, int M, int N, int K, int relu, int obf16)
{
    __shared__ ushort As[128 * LDT];
    __shared__ ushort Bs[128 * LDT];

    const int tid = threadIdx.x;
    const int m0 = blockIdx.y * 128, n0 = blockIdx.x * 128;
    const int lane = tid & 63, w = tid >> 6;
    const int wm = (w & 1) * 64, wn = (w >> 1) * 64;
    const int quad = lane >> 4, l16 = lane & 15;

    const int srow = tid >> 1, scol = (tid & 1) * 16;

    float4v acc[4][4] = {};

    for (int k0 = 0; k0 < K; k0 += 32) {
        // stage A tile: rows always valid (M % 128 == 0)
        {
            const ushort* src = A + (size_t)(m0 + srow) * K + k0 + scol;
            *(short8*)(As + srow * LDT + scol)     = *(const short8*)(src);
            *(short8*)(As + srow * LDT + scol + 8) = *(const short8*)(src + 8);
        }
        // stage B tile (Wt rows guarded against N)
        {
            int n = n0 + srow;
            short8 v0, v1;
            if (n < N) {
                const ushort* src = Wt + (size_t)n * K + k0 + scol;
                v0 = *(const short8*)(src);
                v1 = *(const short8*)(src + 8);
            } else {
#pragma unroll
                for (int i = 0; i < 8; ++i) { v0[i] = 0; v1[i] = 0; }
            }
            *(short8*)(Bs + srow * LDT + scol)     = v0;
            *(short8*)(Bs + srow * LDT + scol + 8) = v1;
        }
        __syncthreads();

        short8 af[4], bfr[4];
#pragma unroll
        for (int i = 0; i < 4; ++i) {
            af[i]  = *(const short8*)(As + (wm + i * 16 + l16) * LDT + quad * 8);
            bfr[i] = *(const short8*)(Bs + (wn + i * 16 + l16) * LDT + quad * 8);
        }
#pragma unroll
        for (int mi = 0; mi < 4; ++mi)
#pragma unroll
            for (int ni = 0; ni < 4; ++ni)
                acc[mi][ni] = __builtin_amdgcn_mfma_f32_16x16x32_bf16(
                    af[mi], bfr[ni], acc[mi][ni], 0, 0, 0);
        __syncthreads();
    }

    // epilogue: C/D layout col = lane&15, row = quad*4 + r
    float* outf = (float*)outp;
    ushort* outb = (ushort*)outp;
#pragma unroll
    for (int mi = 0; mi < 4; ++mi) {
#pragma unroll
        for (int ni = 0; ni < 4; ++ni) {
            int col = n0 + wn + ni * 16 + l16;
            if (col >= N) continue;
            float bv = bias[col];
#pragma unroll
            for (int r = 0; r < 4; ++r) {
                int row = m0 + wm + mi * 16 + quad * 4 + r;
                float v = acc[mi][ni][r] + bv;
                if (relu) v = fmaxf(v, 0.f);
                size_t o = (size_t)row * N + col;
                if (res) v += res[o];
                if (obf16) outb[o] = f2bf(v);
                else       outf[o] = v;
            }
        }
    }
}

// ---------------------------------------------------------------------------
// LayerNorm over last dim (768), fp32 in -> bf16 out. One block per token.
// ---------------------------------------------------------------------------
__global__ __launch_bounds__(256) void ln_kernel(
    const float* __restrict__ X, const float* __restrict__ g,
    const float* __restrict__ b, ushort* __restrict__ O)
{
    const int row = blockIdx.x;
    const int t = threadIdx.x;
    const float* x = X + (size_t)row * D_;
    float v0 = x[t], v1 = x[t + 256], v2 = x[t + 512];
    float s  = v0 + v1 + v2;
    float ss = v0 * v0 + v1 * v1 + v2 * v2;
    block_reduce2(s, ss);
    float mean = s * (1.f / D_);
    float var  = ss * (1.f / D_) - mean * mean;
    float rstd = rsqrtf(var + 1e-5f);
    ushort* o = O + (size_t)row * D_;
    o[t]       = f2bf((v0 - mean) * rstd * g[t]       + b[t]);
    o[t + 256] = f2bf((v1 - mean) * rstd * g[t + 256] + b[t + 256]);
    o[t + 512] = f2bf((v2 - mean) * rstd * g[t + 512] + b[t + 512]);
}

// ---------------------------------------------------------------------------
// Assemble token sequence + embedding LayerNorm -> fp32 residual stream X.
// ---------------------------------------------------------------------------
__global__ __launch_bounds__(256) void assemble_ln_kernel(
    const float* __restrict__ pvec, const float* __restrict__ svec,
    const float* __restrict__ gvec, const int* __restrict__ mask,
    const float* __restrict__ mtok, const float* __restrict__ g,
    const float* __restrict__ b, float* __restrict__ O)
{
    const int row = blockIdx.x;            // b*12 + n
    const int bb = row / N_, n = row % N_;
    const int t = threadIdx.x;
    float v0, v1, v2;
    if (n < NP_) {
        if (mask[bb * NP_ + n]) {
            v0 = mtok[t]; v1 = mtok[t + 256]; v2 = mtok[t + 512];
        } else {
            const float* p = pvec + (size_t)(bb * NP_ + n) * D_;
            v0 = p[t]; v1 = p[t + 256]; v2 = p[t + 512];
        }
    } else if (n == NP_) {
        const float* p = svec + (size_t)bb * D_;
        v0 = p[t]; v1 = p[t + 256]; v2 = p[t + 512];
    } else {
        const float* p = gvec + (size_t)bb * D_;
        v0 = p[t]; v1 = p[t + 256]; v2 = p[t + 512];
    }
    float s  = v0 + v1 + v2;
    float ss = v0 * v0 + v1 * v1 + v2 * v2;
    block_reduce2(s, ss);
    float mean = s * (1.f / D_);
    float var  = ss * (1.f / D_) - mean * mean;
    float rstd = rsqrtf(var + 1e-5f);
    float* o = O + (size_t)row * D_;
    o[t]       = (v0 - mean) * rstd * g[t]       + b[t];
    o[t + 256] = (v1 - mean) * rstd * g[t + 256] + b[t + 256];
    o[t + 512] = (v2 - mean) * rstd * g[t + 512] + b[t + 512];
}

// ---------------------------------------------------------------------------
// Fused attention: one wave per (b, head). bf16 QKV in, bf16 out.
// ---------------------------------------------------------------------------
__global__ __launch_bounds__(64) void attn_kernel(
    const ushort* __restrict__ QKV, ushort* __restrict__ OUT)
{
    const int bh = blockIdx.x;
    const int bb = bh / H_, h = bh % H_;
    const int t = threadIdx.x;

    __shared__ float q[N_][HD_], k[N_][HD_], v[N_][HD_], p[N_][N_];

    const ushort* base = QKV + (size_t)bb * N_ * (3 * D_) + h * HD_;
#pragma unroll
    for (int n = 0; n < N_; ++n) {
        q[n][t] = bf2f(base[n * (3 * D_) + t]);
        k[n][t] = bf2f(base[n * (3 * D_) + D_ + t]);
        v[n][t] = bf2f(base[n * (3 * D_) + 2 * D_ + t]);
    }
    __syncthreads();

    if (t < 32) {
        float freq = exp2f(-(float)t * (13.287712379549449f / 32.0f));
#pragma unroll
        for (int n = 0; n < N_; ++n) {
            float ang = (float)n * freq;
            float sn, cs;
            sincosf(ang, &sn, &cs);
            float xr = q[n][2 * t], xi = q[n][2 * t + 1];
            q[n][2 * t]     = xr * cs - xi * sn;
            q[n][2 * t + 1] = xr * sn + xi * cs;
            xr = k[n][2 * t]; xi = k[n][2 * t + 1];
            k[n][2 * t]     = xr * cs - xi * sn;
            k[n][2 * t + 1] = xr * sn + xi * cs;
        }
    }
    __syncthreads();

    for (int idx = t; idx < N_ * N_; idx += 64) {
        int i = idx / N_, j = idx % N_;
        float s = 0.f;
#pragma unroll
        for (int d = 0; d < HD_; ++d) s += q[i][d] * k[j][d];
        p[i][j] = s * 0.125f;
    }
    __syncthreads();

    if (t < N_) {
        float mx = -1e30f;
#pragma unroll
        for (int j = 0; j < N_; ++j) mx = fmaxf(mx, p[t][j]);
        float e[N_], sum = 0.f;
#pragma unroll
        for (int j = 0; j < N_; ++j) { e[j] = expf(p[t][j] - mx); sum += e[j]; }
        float inv = 1.f / sum;
#pragma unroll
        for (int j = 0; j < N_; ++j) p[t][j] = e[j] * inv;
    }
    __syncthreads();

#pragma unroll
    for (int i = 0; i < N_; ++i) {
        float o = 0.f;
#pragma unroll
        for (int j = 0; j < N_; ++j) o += p[i][j] * v[j][t];
        OUT[((size_t)bb * N_ + i) * D_ + h * HD_ + t] = f2bf(o);
    }
}

// ---------------------------------------------------------------------------
// Token-select + bf16 convert: X[B,12,D] fp32 -> XS[B*10, D] bf16.
// grid: (B*NP, 3), block 256
// ---------------------------------------------------------------------------
__global__ __launch_bounds__(256) void tokensel_kernel(
    const float* __restrict__ X, ushort* __restrict__ XS)
{
    const int r = blockIdx.x;                      // 0..10239
    const int c = blockIdx.y * 256 + threadIdx.x;  // 0..767
    XS[(size_t)r * D_ + c] =
        f2bf(X[(size_t)((r / 10) * 12 + (r % 10)) * D_ + c]);
}

// ---------------------------------------------------------------------------
// Loss
// ---------------------------------------------------------------------------
__global__ __launch_bounds__(256) void loss_partial_kernel(
    const float* __restrict__ pred, const float* __restrict__ patches,
    const int* __restrict__ mask, float* __restrict__ part)
{
    const int row = blockIdx.x;           // b*10 + n
    const int t = threadIdx.x;
    if (!mask[row]) {
        if (t == 0) part[row] = 0.f;
        return;
    }
    const int bb = row / NP_, n = row % NP_;
    float s = 0.f;
    for (int kk = t; kk < C_ * PL_; kk += 256) {
        int c = kk / PL_, pp = kk % PL_;
        float tgt = patches[((size_t)(bb * C_ + c) * NP_ + n) * PL_ + pp];
        float d = pred[(size_t)row * (C_ * PL_) + kk] - tgt;
        s += d * d;
    }
    float dummy = 0.f;
    block_reduce2(s, dummy);
    if (t == 0) part[row] = s;
}

__global__ __launch_bounds__(256) void loss_final_kernel(
    const float* __restrict__ part, const int* __restrict__ mask,
    float* __restrict__ out)
{
    const int t = threadIdx.x;
    float s = 0.f, cnt = 0.f;
    for (int i = t; i < B_ * NP_; i += 256) {
        s += part[i];
        cnt += (float)mask[i];
    }
    block_reduce2(s, cnt);
    if (t == 0) out[0] = s / (cnt * (float)(C_ * PL_));
}

// ---------------------------------------------------------------------------
// Host launch
// ---------------------------------------------------------------------------
extern "C" void kernel_launch(void* const* d_in, const int* in_sizes, int n_in,
                              void* d_out, int out_size, void* d_ws, size_t ws_size,
                              hipStream_t stream) {
    const float* patches = (const float*)d_in[0];
    const float* stats   = (const float*)d_in[1];
    const float* topo    = (const float*)d_in[2];
    const int*   mask    = (const int*)d_in[3];
    const float* patch_w = (const float*)d_in[4];
    const float* patch_b = (const float*)d_in[5];
    const float* stat_w  = (const float*)d_in[6];
    const float* stat_b  = (const float*)d_in[7];
    const float* topo_w  = (const float*)d_in[8];
    const float* topo_b  = (const float*)d_in[9];
    const float* mtok    = (const float*)d_in[10];
    const float* emb_g   = (const float*)d_in[11];
    const float* emb_b   = (const float*)d_in[12];
    const float* ln1_g   = (const float*)d_in[13];
    const float* ln1_b   = (const float*)d_in[14];
    const float* qkv_w   = (const float*)d_in[15];
    const float* qkv_b   = (const float*)d_in[16];
    const float* proj_w  = (const float*)d_in[17];
    const float* proj_b  = (const float*)d_in[18];
    const float* ln2_g   = (const float*)d_in[19];
    const float* ln2_b   = (const float*)d_in[20];
    const float* f1_w    = (const float*)d_in[21];
    const float* f1_b    = (const float*)d_in[22];
    const float* f2_w    = (const float*)d_in[23];
    const float* f2_b    = (const float*)d_in[24];
    const float* h1_w    = (const float*)d_in[25];
    const float* h1_b    = (const float*)d_in[26];
    const float* h2_w    = (const float*)d_in[27];
    const float* h2_b    = (const float*)d_in[28];

    // ---- workspace layout (~228 MB) ----
    const size_t XSZ = (size_t)B_ * N_ * D_;              // 9,437,184
    float*  X    = (float*)d_ws;                          // fp32 residual
    ushort* HB   = (ushort*)(X + XSZ);                    // bf16 LN/attn buf
    ushort* BIGS = HB + XSZ;                              // 28,311,552 shorts
    float*  PART = (float*)(BIGS + (size_t)B_ * N_ * 3 * D_);
    ushort* WB   = (ushort*)(PART + (size_t)B_ * NP_);

    // bf16 transposed weights
    ushort* qkvT  = WB;
    ushort* projT = qkvT + (size_t)L_ * 3 * D_ * D_;
    ushort* f1T   = projT + (size_t)L_ * D_ * D_;
    ushort* f2T   = f1T + (size_t)L_ * 2 * D_ * D_;
    ushort* h1T   = f2T + (size_t)L_ * 2 * D_ * D_;
    ushort* h2T   = h1T + (size_t)D_ * D_;

    // BIGS region reuse (lifetimes disjoint):
    ushort* QKV  = BIGS;                                  // [12288,2304] bf16
    float*  PVEC = (float*)BIGS;                          // [10240,768] fp32 (embed)
    float*  SVEC = PVEC + (size_t)B_ * NP_ * D_;
    float*  GVEC = SVEC + (size_t)B_ * D_;
    ushort* MID  = BIGS;                                  // [12288,1536] bf16 (FFN)
    float*  PRED = (float*)BIGS;                          // [10240,300] fp32 (head)
    ushort* XS   = BIGS + (size_t)2 * B_ * NP_ * 300;     // [10240,768] bf16
    ushort* PMID = XS + (size_t)B_ * NP_ * D_;            // [10240,768] bf16

    const dim3 blk(256);

    // ---- weight convert+transpose (bf16 [N,K]) ----
    for (int l = 0; l < L_; ++l) {
        transpose_bf16<<<dim3(2304 / 32, 768 / 32), blk, 0, stream>>>(
            qkv_w + (size_t)l * D_ * 3 * D_, qkvT + (size_t)l * 3 * D_ * D_, D_, 3 * D_);
        transpose_bf16<<<dim3(768 / 32, 768 / 32), blk, 0, stream>>>(
            proj_w + (size_t)l * D_ * D_, projT + (size_t)l * D_ * D_, D_, D_);
        transpose_bf16<<<dim3(1536 / 32, 768 / 32), blk, 0, stream>>>(
            f1_w + (size_t)l * D_ * 2 * D_, f1T + (size_t)l * 2 * D_ * D_, D_, 2 * D_);
        transpose_bf16<<<dim3(768 / 32, 1536 / 32), blk, 0, stream>>>(
            f2_w + (size_t)l * 2 * D_ * D_, f2T + (size_t)l * 2 * D_ * D_, 2 * D_, D_);
    }
    transpose_bf16<<<dim3(768 / 32, 768 / 32), blk, 0, stream>>>(h1_w, h1T, D_, D_);
    transpose_bf16<<<dim3(10, 768 / 32), blk, 0, stream>>>(h2_w, h2T, D_, C_ * PL_);

    // ---- embed (small K; fp32 path) ----
    gemm_kernel<<<dim3(D_ / 64, (B_ * NP_) / 64), blk, 0, stream>>>(
        patches, patch_w, patch_b, nullptr, PVEC, B_ * NP_, D_, C_ * PL_, 2, 0);
    gemm_kernel<<<dim3(D_ / 64, B_ / 64), blk, 0, stream>>>(
        stats, stat_w, stat_b, nullptr, SVEC, B_, D_, 56, 0, 0);
    gemm_kernel<<<dim3(D_ / 64, B_ / 64), blk, 0, stream>>>(
        topo, topo_w, topo_b, nullptr, GVEC, B_, D_, 24, 0, 0);
    assemble_ln_kernel<<<B_ * N_, blk, 0, stream>>>(
        PVEC, SVEC, GVEC, mask, mtok, emb_g, emb_b, X);

    // ---- transformer layers ----
    for (int l = 0; l < L_; ++l) {
        ln_kernel<<<B_ * N_, blk, 0, stream>>>(X, ln1_g + l * D_, ln1_b + l * D_, HB);
        mfma_gemm<<<dim3(18, 96), blk, 0, stream>>>(
            HB, qkvT + (size_t)l * 3 * D_ * D_, qkv_b + l * 3 * D_, nullptr, QKV,
            B_ * N_, 3 * D_, D_, 0, 1);
        attn_kernel<<<B_ * H_, dim3(64), 0, stream>>>(QKV, HB);
        mfma_gemm<<<dim3(6, 96), blk, 0, stream>>>(
            HB, projT + (size_t)l * D_ * D_, proj_b + l * D_, X, X,
            B_ * N_, D_, D_, 0, 0);
        ln_kernel<<<B_ * N_, blk, 0, stream>>>(X, ln2_g + l * D_, ln2_b + l * D_, HB);
        mfma_gemm<<<dim3(12, 96), blk, 0, stream>>>(
            HB, f1T + (size_t)l * 2 * D_ * D_, f1_b + l * 2 * D_, nullptr, MID,
            B_ * N_, 2 * D_, D_, 1, 1);
        mfma_gemm<<<dim3(6, 96), blk, 0, stream>>>(
            MID, f2T + (size_t)l * 2 * D_ * D_, f2_b + l * D_, X, X,
            B_ * N_, D_, 2 * D_, 0, 0);
    }

    // ---- head + loss ----
    tokensel_kernel<<<dim3(B_ * NP_, 3), blk, 0, stream>>>(X, XS);
    mfma_gemm<<<dim3(6, 80), blk, 0, stream>>>(
        XS, h1T, h1_b, nullptr, PMID, B_ * NP_, D_, D_, 1, 1);
    mfma_gemm<<<dim3(3, 80), blk, 0, stream>>>(
        PMID, h2T, h2_b, nullptr, PRED, B_ * NP_, C_ * PL_, D_, 0, 0);
    loss_partial_kernel<<<B_ * NP_, blk, 0, stream>>>(PRED, patches, mask, PART);
    loss_final_kernel<<<1, blk, 0, stream>>>(PART, mask, (float*)d_out);
}

// Round 4
// 4714.292 us; speedup vs baseline: 4.4568x; 1.1170x over previous
//
#include <hip/hip_runtime.h>
#include <hip/hip_bf16.h>
#include <cstddef>

// Problem constants
#define B_   1024
#define C_   3
#define NP_  10
#define PL_  100
#define D_   768
#define H_   12
#define L_   12
#define N_   12   // NP + 2
#define HD_  64

typedef __attribute__((ext_vector_type(8))) short short8;   // 8 x bf16 (4 VGPRs)
typedef __attribute__((ext_vector_type(4))) float float4v;  // 4 x f32 acc

__device__ __forceinline__ ushort f2bf(float x) {
    __hip_bfloat16 h = __float2bfloat16(x);
    return *(ushort*)&h;
}
__device__ __forceinline__ float bf2f(ushort u) {
    union { unsigned u32; float f; } x; x.u32 = ((unsigned)u) << 16; return x.f;
}

// async global->LDS 16B copy: per-lane global addr, wave-uniform LDS base,
// HW writes lane i at base + i*16.
__device__ __forceinline__ void async_cp16(const ushort* g, ushort* lds) {
    __builtin_amdgcn_global_load_lds(
        (const __attribute__((address_space(1))) unsigned int*)g,
        (__attribute__((address_space(3))) unsigned int*)lds, 16, 0, 0);
}

// ---------------------------------------------------------------------------
// Block-wide reduction of two floats across 256 threads (4 waves of 64).
// ---------------------------------------------------------------------------
__device__ __forceinline__ void block_reduce2(float& a, float& b) {
    __shared__ float sa[4], sb[4];
#pragma unroll
    for (int off = 32; off > 0; off >>= 1) {
        a += __shfl_down(a, off);
        b += __shfl_down(b, off);
    }
    int wid = threadIdx.x >> 6, lane = threadIdx.x & 63;
    __syncthreads();
    if (lane == 0) { sa[wid] = a; sb[wid] = b; }
    __syncthreads();
    if (threadIdx.x == 0) {
        float ta = 0.f, tb = 0.f;
#pragma unroll
        for (int i = 0; i < 4; ++i) { ta += sa[i]; tb += sb[i]; }
        sa[0] = ta; sb[0] = tb;
    }
    __syncthreads();
    a = sa[0]; b = sb[0];
}

// ---------------------------------------------------------------------------
// fp32 tiled GEMM — only for the tiny stats/topo embeds (K=56/24).
// ---------------------------------------------------------------------------
#define BM 64
#define BN 64
#define BK 16

__global__ __launch_bounds__(256) void gemm_kernel(
    const float* __restrict__ A, const float* __restrict__ W,
    const float* __restrict__ bias, float* __restrict__ C,
    int M, int N, int K)
{
    __shared__ float As[BK][BM];
    __shared__ float Ws[BK][BN];

    const int tid = threadIdx.x;
    const int tx = tid & 15, ty = tid >> 4;
    const int m0 = blockIdx.y * BM, n0 = blockIdx.x * BN;

    float acc[4][4] = {};

    const int am  = tid & 63;
    const int akq = tid >> 6;
    const int wn  = (tid & 15) * 4;
    const int wk  = tid >> 4;

    for (int k0 = 0; k0 < K; k0 += BK) {
        float4 av = make_float4(0.f, 0.f, 0.f, 0.f);
        int gm = m0 + am;
        int gk = k0 + akq * 4;
        if (gm < M && gk + 3 < K)
            av = *(const float4*)(A + (size_t)gm * K + gk);
        else if (gm < M) {
            float tmp[4] = {0.f, 0.f, 0.f, 0.f};
            for (int i = 0; i < 4; ++i)
                if (gk + i < K) tmp[i] = A[(size_t)gm * K + gk + i];
            av = make_float4(tmp[0], tmp[1], tmp[2], tmp[3]);
        }
        As[akq * 4 + 0][am] = av.x;
        As[akq * 4 + 1][am] = av.y;
        As[akq * 4 + 2][am] = av.z;
        As[akq * 4 + 3][am] = av.w;

        float4 wv = make_float4(0.f, 0.f, 0.f, 0.f);
        int gkw = k0 + wk, gn = n0 + wn;
        if (gkw < K && gn < N)
            wv = *(const float4*)(W + (size_t)gkw * N + gn);
        *(float4*)&Ws[wk][wn] = wv;

        __syncthreads();

#pragma unroll
        for (int kk = 0; kk < BK; ++kk) {
            float4 a = *(const float4*)&As[kk][ty * 4];
            float4 b = *(const float4*)&Ws[kk][tx * 4];
            acc[0][0] += a.x * b.x; acc[0][1] += a.x * b.y; acc[0][2] += a.x * b.z; acc[0][3] += a.x * b.w;
            acc[1][0] += a.y * b.x; acc[1][1] += a.y * b.y; acc[1][2] += a.y * b.z; acc[1][3] += a.y * b.w;
            acc[2][0] += a.z * b.x; acc[2][1] += a.z * b.y; acc[2][2] += a.z * b.z; acc[2][3] += a.z * b.w;
            acc[3][0] += a.w * b.x; acc[3][1] += a.w * b.y; acc[3][2] += a.w * b.z; acc[3][3] += a.w * b.w;
        }
        __syncthreads();
    }

#pragma unroll
    for (int i = 0; i < 4; ++i) {
        int row = m0 + ty * 4 + i;
        if (row >= M) continue;
#pragma unroll
        for (int j = 0; j < 4; ++j) {
            int col = n0 + tx * 4 + j;
            if (col >= N) continue;
            C[(size_t)row * N + col] = acc[i][j] + bias[col];
        }
    }
}

// ---------------------------------------------------------------------------
// Batched weight convert+transpose: fp32 [K,N] -> bf16 [Npad, Kpad]
// (zero-filled in [N,Npad) rows and [K,Kpad) cols). blockIdx.z = batch.
// ---------------------------------------------------------------------------
__global__ __launch_bounds__(256) void transpose_bf16_b(
    const float* __restrict__ in, ushort* __restrict__ out,
    int K, int N, int Kpad, int Npad, size_t in_stride, size_t out_stride)
{
    __shared__ float t[32][33];
    const float* inz = in + (size_t)blockIdx.z * in_stride;
    ushort* outz = out + (size_t)blockIdx.z * out_stride;
    const int tx = threadIdx.x & 31, ty = threadIdx.x >> 5;  // 32 x 8
    const int k0 = blockIdx.y * 32, n0 = blockIdx.x * 32;
#pragma unroll
    for (int i = 0; i < 4; ++i) {
        int k = k0 + ty + i * 8, n = n0 + tx;
        t[ty + i * 8][tx] = (k < K && n < N) ? inz[(size_t)k * N + n] : 0.f;
    }
    __syncthreads();
#pragma unroll
    for (int i = 0; i < 4; ++i) {
        int n = n0 + ty + i * 8, k = k0 + tx;
        if (n < Npad && k < Kpad)
            outz[(size_t)n * Kpad + k] = f2bf(t[tx][ty + i * 8]);
    }
}

// ---------------------------------------------------------------------------
// Patch gather -> bf16 A matrix [B*NP, 320] (zero-padded cols 300..319).
// row=(b,n), col=c*100+p ; patches layout [B,C,NP,PL].
// ---------------------------------------------------------------------------
__global__ __launch_bounds__(256) void patch_gather(
    const float* __restrict__ patches, ushort* __restrict__ PB)
{
    int idx = blockIdx.x * 256 + threadIdx.x;   // B*NP*320
    int row = idx / 320, col = idx % 320;
    ushort v = 0;
    if (col < 300) {
        int bb = row / 10, n = row % 10, c = col / 100, p = col % 100;
        v = f2bf(patches[(size_t)((bb * 3 + c) * 10 + n) * 100 + p]);
    }
    PB[idx] = v;
}

// ---------------------------------------------------------------------------
// bf16 MFMA GEMM (m97-style): out[M,N] = A[M,K] @ Wt[Npad,K]^T + bias (+res)
// 128x128 tile, BK=32; staging via global_load_lds width=16 (wave-uniform LDS
// base + lane*16 -> unpadded 128x32 LDS tiles). M % 128 == 0, K % 32 == 0,
// Wt has >= gridDim.x*128 valid (zero-padded) rows. Store guard on col < N.
// ---------------------------------------------------------------------------
__global__ __launch_bounds__(256) void mfma_gemm(
    const ushort* __restrict__ A, const ushort* __restrict__ Wt,
    const float* __restrict__ bias, const float* __restrict__ res,
    void* __restrict__ outp, int M, int N, int K, int relu, int obf16)
{
    __shared__ ushort As[128 * 32];
    __shared__ ushort Bs[128 * 32];

    const int tid = threadIdx.x;
    const int m0 = blockIdx.y * 128, n0 = blockIdx.x * 128;
    const int lane = tid & 63, w = tid >> 6;
    const int wm = (w & 1) * 64, wn = (w >> 1) * 64;
    const int quad = lane >> 4, l16 = lane & 15;

    // staging map: wave w, issue j covers LDS rows j*64 + w*16 .. +15
    const int srow = (w << 4) + (lane >> 2);      // 0..63
    const int scol = (lane & 3) << 3;             // 0,8,16,24 (shorts)
    const size_t arow0 = (size_t)(m0 + srow) * K;
    const size_t arow1 = arow0 + (size_t)64 * K;
    const size_t brow0 = (size_t)(n0 + srow) * K;
    const size_t brow1 = brow0 + (size_t)64 * K;
    ushort* AsW0 = As + (w << 9);                 // w*512 shorts (1024 B)
    ushort* AsW1 = As + 2048 + (w << 9);
    ushort* BsW0 = Bs + (w << 9);
    ushort* BsW1 = Bs + 2048 + (w << 9);

    float4v acc[4][4] = {};

    for (int k0 = 0; k0 < K; k0 += 32) {
        const int kc = k0 + scol;
        async_cp16(A + arow0 + kc, AsW0);
        async_cp16(A + arow1 + kc, AsW1);
        async_cp16(Wt + brow0 + kc, BsW0);
        async_cp16(Wt + brow1 + kc, BsW1);
        __syncthreads();   // drains vmcnt -> LDS tiles complete

        short8 af[4], bfr[4];
#pragma unroll
        for (int i = 0; i < 4; ++i) {
            af[i]  = *(const short8*)(As + (wm + i * 16 + l16) * 32 + quad * 8);
            bfr[i] = *(const short8*)(Bs + (wn + i * 16 + l16) * 32 + quad * 8);
        }
#pragma unroll
        for (int mi = 0; mi < 4; ++mi)
#pragma unroll
            for (int ni = 0; ni < 4; ++ni)
                acc[mi][ni] = __builtin_amdgcn_mfma_f32_16x16x32_bf16(
                    af[mi], bfr[ni], acc[mi][ni], 0, 0, 0);
        __syncthreads();
    }

    // epilogue: C/D layout col = lane&15, row = quad*4 + r
    float* outf = (float*)outp;
    ushort* outb = (ushort*)outp;
#pragma unroll
    for (int mi = 0; mi < 4; ++mi) {
#pragma unroll
        for (int ni = 0; ni < 4; ++ni) {
            int col = n0 + wn + ni * 16 + l16;
            if (col >= N) continue;
            float bv = bias[col];
#pragma unroll
            for (int r = 0; r < 4; ++r) {
                int row = m0 + wm + mi * 16 + quad * 4 + r;
                float v = acc[mi][ni][r] + bv;
                if (relu) v = fmaxf(v, 0.f);
                size_t o = (size_t)row * N + col;
                if (res) v += res[o];
                if (obf16) outb[o] = f2bf(v);
                else       outf[o] = v;
            }
        }
    }
}

// ---------------------------------------------------------------------------
// LayerNorm over last dim (768), fp32 in -> bf16 out. One block per token.
// ---------------------------------------------------------------------------
__global__ __launch_bounds__(256) void ln_kernel(
    const float* __restrict__ X, const float* __restrict__ g,
    const float* __restrict__ b, ushort* __restrict__ O)
{
    const int row = blockIdx.x;
    const int t = threadIdx.x;
    const float* x = X + (size_t)row * D_;
    float v0 = x[t], v1 = x[t + 256], v2 = x[t + 512];
    float s  = v0 + v1 + v2;
    float ss = v0 * v0 + v1 * v1 + v2 * v2;
    block_reduce2(s, ss);
    float mean = s * (1.f / D_);
    float var  = ss * (1.f / D_) - mean * mean;
    float rstd = rsqrtf(var + 1e-5f);
    ushort* o = O + (size_t)row * D_;
    o[t]       = f2bf((v0 - mean) * rstd * g[t]       + b[t]);
    o[t + 256] = f2bf((v1 - mean) * rstd * g[t + 256] + b[t + 256]);
    o[t + 512] = f2bf((v2 - mean) * rstd * g[t + 512] + b[t + 512]);
}

// ---------------------------------------------------------------------------
// Assemble token sequence + embedding LayerNorm -> fp32 residual stream X.
// ---------------------------------------------------------------------------
__global__ __launch_bounds__(256) void assemble_ln_kernel(
    const float* __restrict__ pvec, const float* __restrict__ svec,
    const float* __restrict__ gvec, const int* __restrict__ mask,
    const float* __restrict__ mtok, const float* __restrict__ g,
    const float* __restrict__ b, float* __restrict__ O)
{
    const int row = blockIdx.x;            // b*12 + n
    const int bb = row / N_, n = row % N_;
    const int t = threadIdx.x;
    float v0, v1, v2;
    if (n < NP_) {
        if (mask[bb * NP_ + n]) {
            v0 = mtok[t]; v1 = mtok[t + 256]; v2 = mtok[t + 512];
        } else {
            const float* p = pvec + (size_t)(bb * NP_ + n) * D_;
            v0 = p[t]; v1 = p[t + 256]; v2 = p[t + 512];
        }
    } else if (n == NP_) {
        const float* p = svec + (size_t)bb * D_;
        v0 = p[t]; v1 = p[t + 256]; v2 = p[t + 512];
    } else {
        const float* p = gvec + (size_t)bb * D_;
        v0 = p[t]; v1 = p[t + 256]; v2 = p[t + 512];
    }
    float s  = v0 + v1 + v2;
    float ss = v0 * v0 + v1 * v1 + v2 * v2;
    block_reduce2(s, ss);
    float mean = s * (1.f / D_);
    float var  = ss * (1.f / D_) - mean * mean;
    float rstd = rsqrtf(var + 1e-5f);
    float* o = O + (size_t)row * D_;
    o[t]       = (v0 - mean) * rstd * g[t]       + b[t];
    o[t + 256] = (v1 - mean) * rstd * g[t + 256] + b[t + 256];
    o[t + 512] = (v2 - mean) * rstd * g[t + 512] + b[t + 512];
}

// ---------------------------------------------------------------------------
// Fused attention: one wave per (b, head). bf16 QKV in, bf16 out.
// ---------------------------------------------------------------------------
__global__ __launch_bounds__(64) void attn_kernel(
    const ushort* __restrict__ QKV, ushort* __restrict__ OUT)
{
    const int bh = blockIdx.x;
    const int bb = bh / H_, h = bh % H_;
    const int t = threadIdx.x;

    __shared__ float q[N_][HD_], k[N_][HD_], v[N_][HD_], p[N_][N_];

    const ushort* base = QKV + (size_t)bb * N_ * (3 * D_) + h * HD_;
#pragma unroll
    for (int n = 0; n < N_; ++n) {
        q[n][t] = bf2f(base[n * (3 * D_) + t]);
        k[n][t] = bf2f(base[n * (3 * D_) + D_ + t]);
        v[n][t] = bf2f(base[n * (3 * D_) + 2 * D_ + t]);
    }
    __syncthreads();

    if (t < 32) {
        float freq = exp2f(-(float)t * (13.287712379549449f / 32.0f));
#pragma unroll
        for (int n = 0; n < N_; ++n) {
            float ang = (float)n * freq;
            float sn, cs;
            sincosf(ang, &sn, &cs);
            float xr = q[n][2 * t], xi = q[n][2 * t + 1];
            q[n][2 * t]     = xr * cs - xi * sn;
            q[n][2 * t + 1] = xr * sn + xi * cs;
            xr = k[n][2 * t]; xi = k[n][2 * t + 1];
            k[n][2 * t]     = xr * cs - xi * sn;
            k[n][2 * t + 1] = xr * sn + xi * cs;
        }
    }
    __syncthreads();

    for (int idx = t; idx < N_ * N_; idx += 64) {
        int i = idx / N_, j = idx % N_;
        float s = 0.f;
#pragma unroll
        for (int d = 0; d < HD_; ++d) s += q[i][d] * k[j][d];
        p[i][j] = s * 0.125f;
    }
    __syncthreads();

    if (t < N_) {
        float mx = -1e30f;
#pragma unroll
        for (int j = 0; j < N_; ++j) mx = fmaxf(mx, p[t][j]);
        float e[N_], sum = 0.f;
#pragma unroll
        for (int j = 0; j < N_; ++j) { e[j] = expf(p[t][j] - mx); sum += e[j]; }
        float inv = 1.f / sum;
#pragma unroll
        for (int j = 0; j < N_; ++j) p[t][j] = e[j] * inv;
    }
    __syncthreads();

#pragma unroll
    for (int i = 0; i < N_; ++i) {
        float o = 0.f;
#pragma unroll
        for (int j = 0; j < N_; ++j) o += p[i][j] * v[j][t];
        OUT[((size_t)bb * N_ + i) * D_ + h * HD_ + t] = f2bf(o);
    }
}

// ---------------------------------------------------------------------------
// Token-select + bf16 convert: X[B,12,D] fp32 -> XS[B*10, D] bf16.
// ---------------------------------------------------------------------------
__global__ __launch_bounds__(256) void tokensel_kernel(
    const float* __restrict__ X, ushort* __restrict__ XS)
{
    const int r = blockIdx.x;
    const int c = blockIdx.y * 256 + threadIdx.x;
    XS[(size_t)r * D_ + c] =
        f2bf(X[(size_t)((r / 10) * 12 + (r % 10)) * D_ + c]);
}

// ---------------------------------------------------------------------------
// Loss
// ---------------------------------------------------------------------------
__global__ __launch_bounds__(256) void loss_partial_kernel(
    const float* __restrict__ pred, const float* __restrict__ patches,
    const int* __restrict__ mask, float* __restrict__ part)
{
    const int row = blockIdx.x;
    const int t = threadIdx.x;
    if (!mask[row]) {
        if (t == 0) part[row] = 0.f;
        return;
    }
    const int bb = row / NP_, n = row % NP_;
    float s = 0.f;
    for (int kk = t; kk < C_ * PL_; kk += 256) {
        int c = kk / PL_, pp = kk % PL_;
        float tgt = patches[((size_t)(bb * C_ + c) * NP_ + n) * PL_ + pp];
        float d = pred[(size_t)row * (C_ * PL_) + kk] - tgt;
        s += d * d;
    }
    float dummy = 0.f;
    block_reduce2(s, dummy);
    if (t == 0) part[row] = s;
}

__global__ __launch_bounds__(256) void loss_final_kernel(
    const float* __restrict__ part, const int* __restrict__ mask,
    float* __restrict__ out)
{
    const int t = threadIdx.x;
    float s = 0.f, cnt = 0.f;
    for (int i = t; i < B_ * NP_; i += 256) {
        s += part[i];
        cnt += (float)mask[i];
    }
    block_reduce2(s, cnt);
    if (t == 0) out[0] = s / (cnt * (float)(C_ * PL_));
}

// ---------------------------------------------------------------------------
// Host launch
// ---------------------------------------------------------------------------
extern "C" void kernel_launch(void* const* d_in, const int* in_sizes, int n_in,
                              void* d_out, int out_size, void* d_ws, size_t ws_size,
                              hipStream_t stream) {
    const float* patches = (const float*)d_in[0];
    const float* stats   = (const float*)d_in[1];
    const float* topo    = (const float*)d_in[2];
    const int*   mask    = (const int*)d_in[3];
    const float* patch_w = (const float*)d_in[4];
    const float* patch_b = (const float*)d_in[5];
    const float* stat_w  = (const float*)d_in[6];
    const float* stat_b  = (const float*)d_in[7];
    const float* topo_w  = (const float*)d_in[8];
    const float* topo_b  = (const float*)d_in[9];
    const float* mtok    = (const float*)d_in[10];
    const float* emb_g   = (const float*)d_in[11];
    const float* emb_b   = (const float*)d_in[12];
    const float* ln1_g   = (const float*)d_in[13];
    const float* ln1_b   = (const float*)d_in[14];
    const float* qkv_w   = (const float*)d_in[15];
    const float* qkv_b   = (const float*)d_in[16];
    const float* proj_w  = (const float*)d_in[17];
    const float* proj_b  = (const float*)d_in[18];
    const float* ln2_g   = (const float*)d_in[19];
    const float* ln2_b   = (const float*)d_in[20];
    const float* f1_w    = (const float*)d_in[21];
    const float* f1_b    = (const float*)d_in[22];
    const float* f2_w    = (const float*)d_in[23];
    const float* f2_b    = (const float*)d_in[24];
    const float* h1_w    = (const float*)d_in[25];
    const float* h1_b    = (const float*)d_in[26];
    const float* h2_w    = (const float*)d_in[27];
    const float* h2_b    = (const float*)d_in[28];

    // ---- workspace layout (~229 MB) ----
    const size_t XSZ = (size_t)B_ * N_ * D_;              // 9,437,184
    float*  X    = (float*)d_ws;                          // fp32 residual
    ushort* HB   = (ushort*)(X + XSZ);                    // bf16 LN/attn buf
    ushort* BIGS = HB + XSZ;                              // 28,311,552 shorts
    float*  PART = (float*)(BIGS + (size_t)B_ * N_ * 3 * D_);
    ushort* WB   = (ushort*)(PART + (size_t)B_ * NP_);

    // bf16 transposed weights
    ushort* qkvT  = WB;
    ushort* projT = qkvT + (size_t)L_ * 3 * D_ * D_;
    ushort* f1T   = projT + (size_t)L_ * D_ * D_;
    ushort* f2T   = f1T + (size_t)L_ * 2 * D_ * D_;
    ushort* h1T   = f2T + (size_t)L_ * 2 * D_ * D_;
    ushort* h2T   = h1T + (size_t)D_ * D_;                // [384, 768] padded
    ushort* pwT   = h2T + (size_t)384 * D_;               // [768, 320] padded

    // BIGS region reuse (lifetimes disjoint):
    ushort* QKV  = BIGS;                                  // [12288,2304] bf16
    float*  PVEC = (float*)BIGS;                          // [10240,768] fp32
    float*  SVEC = PVEC + (size_t)B_ * NP_ * D_;
    float*  GVEC = SVEC + (size_t)B_ * D_;
    ushort* PB   = (ushort*)(GVEC + (size_t)B_ * D_);     // [10240,320] bf16
    ushort* MID  = BIGS;                                  // [12288,1536] bf16
    float*  PRED = (float*)BIGS;                          // [10240,300] fp32
    ushort* XS   = BIGS + (size_t)2 * B_ * NP_ * 300;     // [10240,768] bf16
    ushort* PMID = XS + (size_t)B_ * NP_ * D_;            // [10240,768] bf16

    const dim3 blk(256);

    // ---- weight convert+transpose (batched over layers) ----
    transpose_bf16_b<<<dim3(72, 24, L_), blk, 0, stream>>>(
        qkv_w, qkvT, D_, 3 * D_, D_, 3 * D_, (size_t)D_ * 3 * D_, (size_t)3 * D_ * D_);
    transpose_bf16_b<<<dim3(24, 24, L_), blk, 0, stream>>>(
        proj_w, projT, D_, D_, D_, D_, (size_t)D_ * D_, (size_t)D_ * D_);
    transpose_bf16_b<<<dim3(48, 24, L_), blk, 0, stream>>>(
        f1_w, f1T, D_, 2 * D_, D_, 2 * D_, (size_t)D_ * 2 * D_, (size_t)2 * D_ * D_);
    transpose_bf16_b<<<dim3(24, 48, L_), blk, 0, stream>>>(
        f2_w, f2T, 2 * D_, D_, 2 * D_, D_, (size_t)2 * D_ * D_, (size_t)2 * D_ * D_);
    transpose_bf16_b<<<dim3(24, 24, 1), blk, 0, stream>>>(
        h1_w, h1T, D_, D_, D_, D_, 0, 0);
    transpose_bf16_b<<<dim3(12, 24, 1), blk, 0, stream>>>(
        h2_w, h2T, D_, 300, D_, 384, 0, 0);               // pad N to 384
    transpose_bf16_b<<<dim3(24, 10, 1), blk, 0, stream>>>(
        patch_w, pwT, 300, D_, 320, D_, 0, 0);            // pad K to 320

    // ---- embed ----
    patch_gather<<<(B_ * NP_ * 320) / 256, blk, 0, stream>>>(patches, PB);
    mfma_gemm<<<dim3(6, 80), blk, 0, stream>>>(
        PB, pwT, patch_b, nullptr, PVEC, B_ * NP_, D_, 320, 0, 0);
    gemm_kernel<<<dim3(D_ / 64, B_ / 64), blk, 0, stream>>>(
        stats, stat_w, stat_b, SVEC, B_, D_, 56);
    gemm_kernel<<<dim3(D_ / 64, B_ / 64), blk, 0, stream>>>(
        topo, topo_w, topo_b, GVEC, B_, D_, 24);
    assemble_ln_kernel<<<B_ * N_, blk, 0, stream>>>(
        PVEC, SVEC, GVEC, mask, mtok, emb_g, emb_b, X);

    // ---- transformer layers ----
    for (int l = 0; l < L_; ++l) {
        ln_kernel<<<B_ * N_, blk, 0, stream>>>(X, ln1_g + l * D_, ln1_b + l * D_, HB);
        mfma_gemm<<<dim3(18, 96), blk, 0, stream>>>(
            HB, qkvT + (size_t)l * 3 * D_ * D_, qkv_b + l * 3 * D_, nullptr, QKV,
            B_ * N_, 3 * D_, D_, 0, 1);
        attn_kernel<<<B_ * H_, dim3(64), 0, stream>>>(QKV, HB);
        mfma_gemm<<<dim3(6, 96), blk, 0, stream>>>(
            HB, projT + (size_t)l * D_ * D_, proj_b + l * D_, X, X,
            B_ * N_, D_, D_, 0, 0);
        ln_kernel<<<B_ * N_, blk, 0, stream>>>(X, ln2_g + l * D_, ln2_b + l * D_, HB);
        mfma_gemm<<<dim3(12, 96), blk, 0, stream>>>(
            HB, f1T + (size_t)l * 2 * D_ * D_, f1_b + l * 2 * D_, nullptr, MID,
            B_ * N_, 2 * D_, D_, 1, 1);
        mfma_gemm<<<dim3(6, 96), blk, 0, stream>>>(
            MID, f2T + (size_t)l * 2 * D_ * D_, f2_b + l * D_, X, X,
            B_ * N_, D_, 2 * D_, 0, 0);
    }

    // ---- head + loss ----
    tokensel_kernel<<<dim3(B_ * NP_, 3), blk, 0, stream>>>(X, XS);
    mfma_gemm<<<dim3(6, 80), blk, 0, stream>>>(
        XS, h1T, h1_b, nullptr, PMID, B_ * NP_, D_, D_, 1, 1);
    mfma_gemm<<<dim3(3, 80), blk, 0, stream>>>(
        PMID, h2T, h2_b, nullptr, PRED, B_ * NP_, C_ * PL_, D_, 0, 0);
    loss_partial_kernel<<<B_ * NP_, blk, 0, stream>>>(PRED, patches, mask, PART);
    loss_final_kernel<<<1, blk, 0, stream>>>(PART, mask, (float*)d_out);
}